// Round 1
// baseline (509.278 us; speedup 1.0000x reference)
//
#include <hip/hip_runtime.h>
#include <cstdint>
#include <cstddef>

#define NN 8192
#define FIN 256
#define FOUT 128
#define SLOPE 0.2f
#define SHIFT 8.0f

typedef float f32x4 __attribute__((ext_vector_type(4)));
typedef __bf16 bf16x8 __attribute__((ext_vector_type(8)));
typedef int i32x4 __attribute__((ext_vector_type(4)));
typedef unsigned int u32x4 __attribute__((ext_vector_type(4)));

__device__ __forceinline__ unsigned short f2bf(float f) {
  return __builtin_bit_cast(unsigned short, (__bf16)f);
}

// async global->LDS DMA, 16 B/lane; LDS dest = wave-uniform base + lane*16
__device__ __forceinline__ void async_cp16(void* lds, const void* g) {
  __builtin_amdgcn_global_load_lds(
      (const __attribute__((address_space(1))) void*)g,
      (__attribute__((address_space(3))) void*)lds, 16, 0, 0);
}

// ---------------------------------------------------------------------------
// Kernel A: h = x @ W (fp32 acc) -> ht[FOUT][NN] bf16 (transposed), plus fused
// s-reductions and the exp-factor tables (unchanged from v8).
// ---------------------------------------------------------------------------
__global__ __launch_bounds__(256, 4) void k_hw(const float* __restrict__ x,
                                               const float* __restrict__ W,
                                               const float* __restrict__ a1,
                                               const float* __restrict__ a2,
                                               unsigned short* __restrict__ ht,
                                               float* __restrict__ Etab,
                                               unsigned short* __restrict__ FbfF,
                                               unsigned short* __restrict__ FbfF2) {
  __shared__ float xs[8][256];
  __shared__ unsigned short tile[128][8];   // [f][row]
  const int tid = threadIdx.x;
  const int rowbase = blockIdx.x * 8;

  #pragma unroll
  for (int it = 0; it < 2; ++it) {
    int fi = it * 1024 + tid * 4;
    int r = fi >> 8, k = fi & 255;
    *(f32x4*)&xs[r][k] = *(const f32x4*)(x + (size_t)(rowbase + r) * FIN + k);
  }
  __syncthreads();

  const int r = tid >> 5;    // 0..7
  const int cg = tid & 31;   // cols cg*4..cg*4+3
  f32x4 acc = {0.f, 0.f, 0.f, 0.f};

  #pragma unroll 8
  for (int k = 0; k < FIN; ++k) {
    f32x4 wv = *(const f32x4*)(W + k * FOUT + cg * 4);
    float xv = xs[r][k];
    acc[0] += xv * wv[0];
    acc[1] += xv * wv[1];
    acc[2] += xv * wv[2];
    acc[3] += xv * wv[3];
  }

  #pragma unroll
  for (int c = 0; c < 4; ++c) tile[cg * 4 + c][r] = f2bf(acc[c]);

  // fused s-vectors
  f32x4 av1 = *(const f32x4*)(a1 + cg * 4);
  f32x4 av2 = *(const f32x4*)(a2 + cg * 4);
  float s1 = acc[0] * av1[0] + acc[1] * av1[1] + acc[2] * av1[2] + acc[3] * av1[3];
  float s2 = acc[0] * av2[0] + acc[1] * av2[1] + acc[2] * av2[2] + acc[3] * av2[3];
  #pragma unroll
  for (int off = 16; off > 0; off >>= 1) {
    s1 += __shfl_xor(s1, off, 64);
    s2 += __shfl_xor(s2, off, 64);
  }
  if (cg == 0) {
    const int row = rowbase + r;
    float c0 = s1 + SHIFT;
    float c = fmaxf(c0, SLOPE * c0);
    Etab[(size_t)row * 2]     = __expf(s1 - c);
    Etab[(size_t)row * 2 + 1] = __expf(SLOPE * s1 - c);
    FbfF[row]  = f2bf(__expf(s2));
    FbfF2[row] = f2bf(__expf(SLOPE * s2));
  }
  __syncthreads();

  if (tid < 128) {
    u32x4 v = *(const u32x4*)&tile[tid][0];
    *(u32x4*)(ht + (size_t)tid * NN + rowbase) = v;
  }
}

// ---------------------------------------------------------------------------
// k_zero: zero the numerator accumulator (out) and denominator workspace.
// ---------------------------------------------------------------------------
__global__ __launch_bounds__(256) void k_zero(float* __restrict__ outacc,
                                              float* __restrict__ dws) {
  const int i = blockIdx.x * 256 + threadIdx.x;   // grid covers NN*FOUT/4 exactly
  f32x4 z = {0.f, 0.f, 0.f, 0.f};
  ((f32x4*)outacc)[i] = z;
  if (i < NN / 4) ((f32x4*)dws)[i] = z;
}

// ---------------------------------------------------------------------------
// Kernel B: fused masked-softmax aggregation, v9.
// Delta vs v8 (478 us session best; k_gat 180 us, VALUBusy 43%, Occ 21%):
//  * COLUMN-SPLIT GRID: 1024 blocks = 512 row-groups x 2 column halves
//    (16 rows x 4096 cols each) -> 4 blocks/CU instead of the grid-capped 2.
//    Independent per-block barriers desynchronize -> fills the 57% idle
//    SIMD slots seen at 2 waves/SIMD.
//  * adj staging moved LDS -> registers with one-chunk ping-pong prefetch
//    (sA dropped; LDS 41.5 KB -> 33.3 KB so 4 blocks/CU fit). The per-chunk
//    barrier's implicit vmcnt(0) drain is the prefetch fence, same pipeline
//    discipline as the ht DMA.
//  * Two-stage finish: atomicAdd partial numerator into out, partial den
//    into dws (exactly 2 addends per address -> order-independent,
//    deterministic), then k_fin does num/den + bias.
//  * sH is per-wave private (wave w stages AND reads features 32w..32w+31),
//    so the only cross-wave LDS is sF, which keeps the barrier-separated
//    double buffer.
// ---------------------------------------------------------------------------
__global__ __launch_bounds__(256, 4) void k_gat(const int* __restrict__ adj,
                                                const unsigned short* __restrict__ ht,
                                                const float* __restrict__ Etab,
                                                const unsigned short* __restrict__ FbfF,
                                                const unsigned short* __restrict__ FbfF2,
                                                float* __restrict__ outacc,
                                                float* __restrict__ dws) {
  __shared__ unsigned short sH[2][128 * 64]; // 32 KB : ht, slot s holds group s^(f&7)
  __shared__ unsigned short sF[2][128];      // 512 B : [0,64)=F plane, [64,128)=F2

  const int tid = threadIdx.x;
  const int wave = tid >> 6;
  const int lane = tid & 63;
  const int quad = lane >> 4;
  const int m = lane & 15;                   // A-row / B-col label
  const int rowbase = (int)(blockIdx.x >> 1) * 16;
  const int colbase = (int)(blockIdx.x & 1) * (NN / 2);
  const int row = rowbase + m;

  // ---- runtime layout probes (exact in bf16/fp32) ----
  bf16x8 pm, pinv, pones;
  #pragma unroll
  for (int jj = 0; jj < 8; ++jj) {
    pm[jj] = (__bf16)(float)m;
    pinv[jj] = (__bf16)0.03125f;
    pones[jj] = (__bf16)1.0f;
  }
  f32x4 z = {0.f, 0.f, 0.f, 0.f};
  f32x4 rp = __builtin_amdgcn_mfma_f32_16x16x32_bf16(pm, pinv, z, 0, 0, 0);
  f32x4 cp = __builtin_amdgcn_mfma_f32_16x16x32_bf16(pinv, pm, z, 0, 0, 0);
  int rowmap[4], colmap[4];
  #pragma unroll
  for (int r = 0; r < 4; ++r) {
    rowmap[r] = ((int)(rp[r] + 0.5f)) & 15;
    colmap[r] = ((int)(cp[r] + 0.5f)) & 15;
  }

  const float E  = Etab[(size_t)row * 2];
  const float E2 = Etab[(size_t)row * 2 + 1];
  const int t0 = wave * 2, t1 = wave * 2 + 1;

  f32x4 acc0 = z, acc1 = z, den = z;

  // ---- loop-carried per-lane DMA source pointers (ht) ----
  const unsigned short* srcH[4];
  #pragma unroll
  for (int il = 0; il < 4; ++il) {
    const int i = wave * 4 + il;
    const int f = i * 8 + (lane >> 3);
    const int g = (lane & 7) ^ (lane >> 3);
    srcH[il] = ht + (size_t)f * NN + colbase + g * 8;
  }
  // F planes: wave 1, lanes 0..15 -> sF[0..255 B]
  const unsigned short* srcF = nullptr;
  if (wave == 1) {
    srcF = (lane < 8) ? (FbfF + colbase + lane * 8)
                      : (FbfF2 + colbase + (lane - 8) * 8);
  }

  auto stage = [&](int b) {
    #pragma unroll
    for (int il = 0; il < 4; ++il) {
      async_cp16(&sH[b][(wave * 4 + il) * 512], srcH[il]);
      srcH[il] += 64;
    }
    if (wave == 1 && lane < 16) {
      async_cp16(&sF[b][0], srcF);
      srcF += 64;
    }
  };

  // adj direct-to-register: per chunk, lane needs row m, cols
  // {k32*32 + quad*8 + 0..7} for k32=0,1 -> 4x dwordx4, all 16B-aligned.
  const int* arow = adj + (size_t)row * NN + colbase + quad * 8;
  auto load_adj = [&](i32x4* d, int c) {
    const int* p = arow + c * 64;
    d[0] = *(const i32x4*)(p);
    d[1] = *(const i32x4*)(p + 4);
    d[2] = *(const i32x4*)(p + 32);
    d[3] = *(const i32x4*)(p + 36);
  };

  auto compute = [&](int cs, const i32x4* av) {
    #pragma unroll
    for (int k32 = 0; k32 < 2; ++k32) {
      const int jl = k32 * 32 + quad * 8;
      u32x4 Fq = *(const u32x4*)&sF[cs][jl];        // 8 bf16 F
      u32x4 Gq = *(const u32x4*)&sF[cs][64 + jl];   // 8 bf16 F2
      const i32x4 A0 = av[k32 * 2];
      const i32x4 A1 = av[k32 * 2 + 1];

      bf16x8 af;
      #pragma unroll
      for (int p = 0; p < 4; ++p) {
        const unsigned fp = Fq[p], gp = Gq[p];
        const float Flo = __builtin_bit_cast(float, fp << 16);
        const float Fhi = __builtin_bit_cast(float, fp & 0xffff0000u);
        const float Glo = __builtin_bit_cast(float, gp << 16);
        const float Ghi = __builtin_bit_cast(float, gp & 0xffff0000u);
        const float wlo = fmaxf(E * Flo, E2 * Glo);
        const float whi = fmaxf(E * Fhi, E2 * Ghi);
        const int avlo = (p < 2) ? A0[p * 2] : A1[p * 2 - 4];
        const int avhi = (p < 2) ? A0[p * 2 + 1] : A1[p * 2 - 3];
        af[p * 2]     = avlo ? (__bf16)wlo : (__bf16)0.0f;
        af[p * 2 + 1] = avhi ? (__bf16)whi : (__bf16)0.0f;
      }

      // ht frags: tile t, slot s = (4k32+quad) ^ (m&7)
      const int s0 = (k32 * 4 + quad) ^ (m & 7);
      bf16x8 b0 = __builtin_bit_cast(bf16x8,
          *(const u32x4*)&sH[cs][(t0 * 16 + m) * 64 + s0 * 8]);
      bf16x8 b1 = __builtin_bit_cast(bf16x8,
          *(const u32x4*)&sH[cs][(t1 * 16 + m) * 64 + s0 * 8]);

      acc0 = __builtin_amdgcn_mfma_f32_16x16x32_bf16(af, b0, acc0, 0, 0, 0);
      acc1 = __builtin_amdgcn_mfma_f32_16x16x32_bf16(af, b1, acc1, 0, 0, 0);
      den  = __builtin_amdgcn_mfma_f32_16x16x32_bf16(af, pones, den, 0, 0, 0);
    }
  };

  i32x4 aA[4], aB[4];
  load_adj(aA, 0);
  stage(0);   // chunk 0 -> buffer 0

  // 64 chunks of 64 cols over this block's 4096-col half; barrier-per-chunk,
  // prefetch (DMA + adj regs) flies across one compute phase.
  #pragma unroll 1
  for (int c = 0; c < 64; c += 2) {
    __syncthreads();                 // drains chunk c DMA + adj regs for c
    stage(1);                        // prefetch chunk c+1
    load_adj(aB, c + 1);
    compute(0, aA);                  // chunk c (buffer 0)
    __syncthreads();                 // drains chunk c+1; fences buf0 readers
    if (c + 2 < 64) {
      stage(0);                      // prefetch chunk c+2
      load_adj(aA, c + 2);
    }
    compute(1, aB);                  // chunk c+1 (buffer 1)
  }

  // ---- epilogue: atomic partial accumulation (2 addends/address total) ----
  #pragma unroll
  for (int r = 0; r < 4; ++r) {
    const int orow = rowbase + rowmap[r];
    const int c0 = t0 * 16 + colmap[r];
    const int c1 = t1 * 16 + colmap[r];
    atomicAdd(&outacc[(size_t)orow * FOUT + c0], acc0[r]);
    atomicAdd(&outacc[(size_t)orow * FOUT + c1], acc1[r]);
  }
  // den is identical across waves and across the 16 m-lanes: add once/row.
  if (wave == 0 && m == 0) {
    #pragma unroll
    for (int r = 0; r < 4; ++r) {
      atomicAdd(&dws[rowbase + rowmap[r]], den[r]);
    }
  }
}

// ---------------------------------------------------------------------------
// k_fin: out = num/den + bias
// ---------------------------------------------------------------------------
__global__ __launch_bounds__(256) void k_fin(const float* __restrict__ dws,
                                             const float* __restrict__ bias,
                                             float* __restrict__ out) {
  const int idx = (blockIdx.x * 256 + threadIdx.x) * 4;  // float index
  const int rowi = idx >> 7;
  const int f = idx & 127;
  const float inv = 1.0f / dws[rowi];
  f32x4 v = *(f32x4*)(out + idx);
  f32x4 b = *(const f32x4*)(bias + f);
  v[0] = v[0] * inv + b[0];
  v[1] = v[1] * inv + b[1];
  v[2] = v[2] * inv + b[2];
  v[3] = v[3] * inv + b[3];
  *(f32x4*)(out + idx) = v;
}

// ---------------------------------------------------------------------------
extern "C" void kernel_launch(void* const* d_in, const int* in_sizes, int n_in,
                              void* d_out, int out_size, void* d_ws, size_t ws_size,
                              hipStream_t stream) {
  const float* x    = (const float*)d_in[0];
  const int*   adj  = (const int*)d_in[1];
  const float* W    = (const float*)d_in[2];
  const float* a1   = (const float*)d_in[3];
  const float* a2   = (const float*)d_in[4];
  const float* bias = (const float*)d_in[5];
  float* out = (float*)d_out;

  char* ws = (char*)d_ws;
  unsigned short* ht = (unsigned short*)ws;                            // 2 MB
  float* Etab = (float*)(ws + (size_t)2 * 1024 * 1024);                // 64 KB
  unsigned short* FbfF =
      (unsigned short*)(ws + (size_t)2 * 1024 * 1024 + 64 * 1024);     // 16 KB
  unsigned short* FbfF2 = FbfF + NN;                                   // 16 KB
  float* dws = (float*)(ws + (size_t)2 * 1024 * 1024 + 96 * 1024);     // 32 KB

  k_zero<<<(NN * FOUT / 4) / 256, 256, 0, stream>>>(out, dws);
  k_hw<<<NN / 8, 256, 0, stream>>>(x, W, a1, a2, ht, Etab, FbfF, FbfF2);
  k_gat<<<(NN / 16) * 2, 256, 0, stream>>>(adj, ht, Etab, FbfF, FbfF2, out, dws);
  k_fin<<<(NN * FOUT / 4) / 256, 256, 0, stream>>>(dws, bias, out);
}

// Round 2
// 464.776 us; speedup vs baseline: 1.0958x; 1.0958x over previous
//
#include <hip/hip_runtime.h>
#include <cstdint>
#include <cstddef>

#define NN 8192
#define FIN 256
#define FOUT 128
#define SLOPE 0.2f
#define SHIFT 8.0f

typedef float f32x4 __attribute__((ext_vector_type(4)));
typedef __bf16 bf16x8 __attribute__((ext_vector_type(8)));
typedef int i32x4 __attribute__((ext_vector_type(4)));
typedef unsigned int u32x4 __attribute__((ext_vector_type(4)));

__device__ __forceinline__ unsigned short f2bf(float f) {
  return __builtin_bit_cast(unsigned short, (__bf16)f);
}

// async global->LDS DMA, 16 B/lane; LDS dest = wave-uniform base + lane*16
__device__ __forceinline__ void async_cp16(void* lds, const void* g) {
  __builtin_amdgcn_global_load_lds(
      (const __attribute__((address_space(1))) void*)g,
      (__attribute__((address_space(3))) void*)lds, 16, 0, 0);
}

// ---------------------------------------------------------------------------
// Kernel A: h = x @ W (fp32 acc) -> ht[FOUT][NN] bf16 (transposed), plus fused
// s-reductions and exp-factor tables. v10: also zeroes out/dws (k_zero folded
// in; the stores are independent and overlap the GEMM).
// ---------------------------------------------------------------------------
__global__ __launch_bounds__(256, 4) void k_hw(const float* __restrict__ x,
                                               const float* __restrict__ W,
                                               const float* __restrict__ a1,
                                               const float* __restrict__ a2,
                                               unsigned short* __restrict__ ht,
                                               float* __restrict__ Etab,
                                               unsigned short* __restrict__ FbfF,
                                               unsigned short* __restrict__ FbfF2,
                                               float* __restrict__ outacc,
                                               float* __restrict__ dws) {
  __shared__ float xs[8][256];
  __shared__ unsigned short tile[128][8];   // [f][row]
  const int tid = threadIdx.x;
  const int rowbase = blockIdx.x * 8;

  // folded k_zero: each block zeroes its 4 KB slice of out + 8 floats of dws
  {
    f32x4 z = {0.f, 0.f, 0.f, 0.f};
    *(f32x4*)(outacc + (size_t)blockIdx.x * 1024 + tid * 4) = z;
    if (tid < 2) *(f32x4*)(dws + blockIdx.x * 8 + tid * 4) = z;
  }

  #pragma unroll
  for (int it = 0; it < 2; ++it) {
    int fi = it * 1024 + tid * 4;
    int r = fi >> 8, k = fi & 255;
    *(f32x4*)&xs[r][k] = *(const f32x4*)(x + (size_t)(rowbase + r) * FIN + k);
  }
  __syncthreads();

  const int r = tid >> 5;    // 0..7
  const int cg = tid & 31;   // cols cg*4..cg*4+3
  f32x4 acc = {0.f, 0.f, 0.f, 0.f};

  #pragma unroll 8
  for (int k = 0; k < FIN; ++k) {
    f32x4 wv = *(const f32x4*)(W + k * FOUT + cg * 4);
    float xv = xs[r][k];
    acc[0] += xv * wv[0];
    acc[1] += xv * wv[1];
    acc[2] += xv * wv[2];
    acc[3] += xv * wv[3];
  }

  #pragma unroll
  for (int c = 0; c < 4; ++c) tile[cg * 4 + c][r] = f2bf(acc[c]);

  // fused s-vectors
  f32x4 av1 = *(const f32x4*)(a1 + cg * 4);
  f32x4 av2 = *(const f32x4*)(a2 + cg * 4);
  float s1 = acc[0] * av1[0] + acc[1] * av1[1] + acc[2] * av1[2] + acc[3] * av1[3];
  float s2 = acc[0] * av2[0] + acc[1] * av2[1] + acc[2] * av2[2] + acc[3] * av2[3];
  #pragma unroll
  for (int off = 16; off > 0; off >>= 1) {
    s1 += __shfl_xor(s1, off, 64);
    s2 += __shfl_xor(s2, off, 64);
  }
  if (cg == 0) {
    const int row = rowbase + r;
    float c0 = s1 + SHIFT;
    float c = fmaxf(c0, SLOPE * c0);
    Etab[(size_t)row * 2]     = __expf(s1 - c);
    Etab[(size_t)row * 2 + 1] = __expf(SLOPE * s1 - c);
    FbfF[row]  = f2bf(__expf(s2));
    FbfF2[row] = f2bf(__expf(SLOPE * s2));
  }
  __syncthreads();

  if (tid < 128) {
    u32x4 v = *(const u32x4*)&tile[tid][0];
    *(u32x4*)(ht + (size_t)tid * NN + rowbase) = v;
  }
}

// ---------------------------------------------------------------------------
// Kernel B: fused masked-softmax aggregation, v10.
// Post-mortem of v9 (206 us, VALUBusy 32%, Occ 37%): column-split occupancy
// gain was real, but moving adj to per-lane register loads made each VMEM
// instruction a 16-row (32 KB stride) scatter: ~32 cache lines/instr x 16
// instrs/chunk (4x wave-redundant) vs the v8 DMA's 4 instrs x 16 contiguous
// lines. The per-CU TA pipe saturated and every wave queued behind it ->
// VALUBusy DROPPED despite more waves. Fix:
//  * adj restored to async global->LDS DMA (v8 pattern + colbase).
//  * F/F2 planes move LDS -> registers with one-chunk ping-pong prefetch
//    (4x16B broadcast loads/wave/chunk, ~1 line each: negligible TA).
//  * LDS = sH 32KB + sA 8KB = 40960 B exactly -> 4 blocks/CU (163840 =
//    the full 160 KiB pool; LDS_Block_Size has matched the request so far).
//  * grid stays 1024 = 512 row-groups x 2 column halves; atomic two-stage
//    finish unchanged (2 addends/address -> deterministic).
// ---------------------------------------------------------------------------
__global__ __launch_bounds__(256, 4) void k_gat(const int* __restrict__ adj,
                                                const unsigned short* __restrict__ ht,
                                                const float* __restrict__ Etab,
                                                const unsigned short* __restrict__ FbfF,
                                                const unsigned short* __restrict__ FbfF2,
                                                float* __restrict__ outacc,
                                                float* __restrict__ dws) {
  __shared__ int sA[2][16 * 64];             // 8 KB  : adj, slot s holds group s^row
  __shared__ unsigned short sH[2][128 * 64]; // 32 KB : ht,  slot s holds group s^(f&7)

  const int tid = threadIdx.x;
  const int wave = tid >> 6;
  const int lane = tid & 63;
  const int quad = lane >> 4;
  const int m = lane & 15;                   // A-row / B-col label
  const int rowbase = (int)(blockIdx.x >> 1) * 16;
  const int colbase = (int)(blockIdx.x & 1) * (NN / 2);
  const int row = rowbase + m;

  // ---- runtime layout probes (exact in bf16/fp32) ----
  bf16x8 pm, pinv, pones;
  #pragma unroll
  for (int jj = 0; jj < 8; ++jj) {
    pm[jj] = (__bf16)(float)m;
    pinv[jj] = (__bf16)0.03125f;
    pones[jj] = (__bf16)1.0f;
  }
  f32x4 z = {0.f, 0.f, 0.f, 0.f};
  f32x4 rp = __builtin_amdgcn_mfma_f32_16x16x32_bf16(pm, pinv, z, 0, 0, 0);
  f32x4 cp = __builtin_amdgcn_mfma_f32_16x16x32_bf16(pinv, pm, z, 0, 0, 0);
  int rowmap[4], colmap[4];
  #pragma unroll
  for (int r = 0; r < 4; ++r) {
    rowmap[r] = ((int)(rp[r] + 0.5f)) & 15;
    colmap[r] = ((int)(cp[r] + 0.5f)) & 15;
  }

  const float E  = Etab[(size_t)row * 2];
  const float E2 = Etab[(size_t)row * 2 + 1];
  const int t0 = wave * 2, t1 = wave * 2 + 1;

  f32x4 acc0 = z, acc1 = z, den = z;

  // ---- loop-carried per-lane DMA source pointers (ht) ----
  const unsigned short* srcH[4];
  #pragma unroll
  for (int il = 0; il < 4; ++il) {
    const int i = wave * 4 + il;
    const int f = i * 8 + (lane >> 3);
    const int g = (lane & 7) ^ (lane >> 3);
    srcH[il] = ht + (size_t)f * NN + colbase + g * 8;
  }
  // adj: waves 2,3, two instrs each; instr slot il: r = 4il + L/16,
  //   slot s = L%16 holds group g = s^r  (coalesced: 256 B/row-quarter)
  const int* srcA[2] = {nullptr, nullptr};
  int slotA[2] = {0, 0};
  if (wave >= 2) {
    #pragma unroll
    for (int q2 = 0; q2 < 2; ++q2) {
      const int il = (wave - 2) * 2 + q2;
      const int r = il * 4 + (lane >> 4);
      const int g = (lane & 15) ^ r;
      slotA[q2] = il;
      srcA[q2] = adj + (size_t)(rowbase + r) * NN + colbase + g * 4;
    }
  }

  auto stage = [&](int b) {
    #pragma unroll
    for (int il = 0; il < 4; ++il) {
      async_cp16(&sH[b][(wave * 4 + il) * 512], srcH[il]);
      srcH[il] += 64;
    }
    if (wave >= 2) {
      #pragma unroll
      for (int q2 = 0; q2 < 2; ++q2) {
        async_cp16(&sA[b][slotA[q2] * 256], srcA[q2]);
        srcA[q2] += 64;
      }
    }
  };

  // F/F2 planes direct-to-register: per chunk, lane needs 8 bf16 at
  // jl = k32*32 + quad*8 from each plane. Quads share addresses (broadcast);
  // across quads one 64 B line -> negligible TA cost.
  const unsigned short* fbase = FbfF  + colbase + quad * 8;
  const unsigned short* gbase = FbfF2 + colbase + quad * 8;
  struct Fregs { u32x4 F0, F1, G0, G1; };
  auto load_f = [&](Fregs& d, int c) {
    const unsigned short* p = fbase + c * 64;
    const unsigned short* q = gbase + c * 64;
    d.F0 = *(const u32x4*)(p);
    d.F1 = *(const u32x4*)(p + 32);
    d.G0 = *(const u32x4*)(q);
    d.G1 = *(const u32x4*)(q + 32);
  };

  auto compute = [&](int cs, const Fregs& fr) {
    #pragma unroll
    for (int k32 = 0; k32 < 2; ++k32) {
      const int g0 = k32 * 8 + quad * 2;
      i32x4 A0 = *(const i32x4*)&sA[cs][m * 64 + ((g0) ^ m) * 4];
      i32x4 A1 = *(const i32x4*)&sA[cs][m * 64 + ((g0 + 1) ^ m) * 4];
      const u32x4 Fq = k32 ? fr.F1 : fr.F0;
      const u32x4 Gq = k32 ? fr.G1 : fr.G0;

      bf16x8 af;
      #pragma unroll
      for (int p = 0; p < 4; ++p) {
        const unsigned fp = Fq[p], gp = Gq[p];
        const float Flo = __builtin_bit_cast(float, fp << 16);
        const float Fhi = __builtin_bit_cast(float, fp & 0xffff0000u);
        const float Glo = __builtin_bit_cast(float, gp << 16);
        const float Ghi = __builtin_bit_cast(float, gp & 0xffff0000u);
        const float wlo = fmaxf(E * Flo, E2 * Glo);
        const float whi = fmaxf(E * Fhi, E2 * Ghi);
        const int avlo = (p < 2) ? A0[p * 2] : A1[p * 2 - 4];
        const int avhi = (p < 2) ? A0[p * 2 + 1] : A1[p * 2 - 3];
        af[p * 2]     = avlo ? (__bf16)wlo : (__bf16)0.0f;
        af[p * 2 + 1] = avhi ? (__bf16)whi : (__bf16)0.0f;
      }

      // ht frags: tile t, slot s = (4k32+quad) ^ (m&7)
      const int s0 = (k32 * 4 + quad) ^ (m & 7);
      bf16x8 b0 = __builtin_bit_cast(bf16x8,
          *(const u32x4*)&sH[cs][(t0 * 16 + m) * 64 + s0 * 8]);
      bf16x8 b1 = __builtin_bit_cast(bf16x8,
          *(const u32x4*)&sH[cs][(t1 * 16 + m) * 64 + s0 * 8]);

      acc0 = __builtin_amdgcn_mfma_f32_16x16x32_bf16(af, b0, acc0, 0, 0, 0);
      acc1 = __builtin_amdgcn_mfma_f32_16x16x32_bf16(af, b1, acc1, 0, 0, 0);
      den  = __builtin_amdgcn_mfma_f32_16x16x32_bf16(af, pones, den, 0, 0, 0);
    }
  };

  Fregs fA, fB;
  load_f(fA, 0);
  stage(0);   // chunk 0 -> buffer 0

  // 64 chunks of 64 cols over this block's 4096-col half; barrier-per-chunk,
  // prefetch (DMA + F regs) flies across one compute phase.
  #pragma unroll 1
  for (int c = 0; c < 64; c += 2) {
    __syncthreads();                 // drains chunk c DMA + F regs for c
    stage(1);                        // prefetch chunk c+1
    load_f(fB, c + 1);
    compute(0, fA);                  // chunk c (buffer 0)
    __syncthreads();                 // drains chunk c+1; fences buf0 readers
    if (c + 2 < 64) {
      stage(0);                      // prefetch chunk c+2
      load_f(fA, c + 2);
    }
    compute(1, fB);                  // chunk c+1 (buffer 1)
  }

  // ---- epilogue: atomic partial accumulation (2 addends/address total) ----
  #pragma unroll
  for (int r = 0; r < 4; ++r) {
    const int orow = rowbase + rowmap[r];
    const int c0 = t0 * 16 + colmap[r];
    const int c1 = t1 * 16 + colmap[r];
    atomicAdd(&outacc[(size_t)orow * FOUT + c0], acc0[r]);
    atomicAdd(&outacc[(size_t)orow * FOUT + c1], acc1[r]);
  }
  // den is identical across waves and across the 16 m-lanes: add once/row.
  if (wave == 0 && m == 0) {
    #pragma unroll
    for (int r = 0; r < 4; ++r) {
      atomicAdd(&dws[rowbase + rowmap[r]], den[r]);
    }
  }
}

// ---------------------------------------------------------------------------
// k_fin: out = num/den + bias
// ---------------------------------------------------------------------------
__global__ __launch_bounds__(256) void k_fin(const float* __restrict__ dws,
                                             const float* __restrict__ bias,
                                             float* __restrict__ out) {
  const int idx = (blockIdx.x * 256 + threadIdx.x) * 4;  // float index
  const int rowi = idx >> 7;
  const int f = idx & 127;
  const float inv = 1.0f / dws[rowi];
  f32x4 v = *(f32x4*)(out + idx);
  f32x4 b = *(const f32x4*)(bias + f);
  v[0] = v[0] * inv + b[0];
  v[1] = v[1] * inv + b[1];
  v[2] = v[2] * inv + b[2];
  v[3] = v[3] * inv + b[3];
  *(f32x4*)(out + idx) = v;
}

// ---------------------------------------------------------------------------
extern "C" void kernel_launch(void* const* d_in, const int* in_sizes, int n_in,
                              void* d_out, int out_size, void* d_ws, size_t ws_size,
                              hipStream_t stream) {
  const float* x    = (const float*)d_in[0];
  const int*   adj  = (const int*)d_in[1];
  const float* W    = (const float*)d_in[2];
  const float* a1   = (const float*)d_in[3];
  const float* a2   = (const float*)d_in[4];
  const float* bias = (const float*)d_in[5];
  float* out = (float*)d_out;

  char* ws = (char*)d_ws;
  unsigned short* ht = (unsigned short*)ws;                            // 2 MB
  float* Etab = (float*)(ws + (size_t)2 * 1024 * 1024);                // 64 KB
  unsigned short* FbfF =
      (unsigned short*)(ws + (size_t)2 * 1024 * 1024 + 64 * 1024);     // 16 KB
  unsigned short* FbfF2 = FbfF + NN;                                   // 16 KB
  float* dws = (float*)(ws + (size_t)2 * 1024 * 1024 + 96 * 1024);     // 32 KB

  k_hw<<<NN / 8, 256, 0, stream>>>(x, W, a1, a2, ht, Etab, FbfF, FbfF2, out, dws);
  k_gat<<<(NN / 16) * 2, 256, 0, stream>>>(adj, ht, Etab, FbfF, FbfF2, out, dws);
  k_fin<<<(NN * FOUT / 4) / 256, 256, 0, stream>>>(dws, bias, out);
}